// Round 7
// baseline (261.851 us; speedup 1.0000x reference)
//
#include <hip/hip_runtime.h>

typedef __bf16 bf16;
typedef float f32x4 __attribute__((ext_vector_type(4)));
typedef bf16 bf16x8v __attribute__((ext_vector_type(8)));
typedef bf16 bf16x4v __attribute__((ext_vector_type(4)));

#define MFMA_BF16(a, b, c) __builtin_amdgcn_mfma_f32_16x16x32_bf16((a), (b), (c), 0, 0, 0)

// async global->LDS, 16B per lane (dest = wave-uniform base + lane*16)
__device__ __forceinline__ void async16(const bf16* g, bf16* l) {
  __builtin_amdgcn_global_load_lds(
      (const __attribute__((address_space(1))) void*)g,
      (__attribute__((address_space(3))) void*)l, 16, 0, 0);
}

// ---------------------------------------------------------------------------
// f32 -> bf16 convert, 8 elements/thread.
// ---------------------------------------------------------------------------
__global__ __launch_bounds__(256) void convert_kernel(
    const float* __restrict__ in, bf16* __restrict__ out, int n8) {
  int i = blockIdx.x * 256 + threadIdx.x;
  if (i >= n8) return;
  const float4* p = (const float4*)in + (size_t)i * 2;
  float4 a = p[0], b = p[1];
  bf16x8v o;
  o[0] = (bf16)a.x; o[1] = (bf16)a.y; o[2] = (bf16)a.z; o[3] = (bf16)a.w;
  o[4] = (bf16)b.x; o[5] = (bf16)b.y; o[6] = (bf16)b.z; o[7] = (bf16)b.w;
  ((bf16x8v*)out)[i] = o;
}

// ---------------------------------------------------------------------------
// Tiled transpose + f32->bf16: out[c][r] = (bf16)in[r][c].  R,C mult of 32.
// ---------------------------------------------------------------------------
__global__ __launch_bounds__(256) void transpose_conv_kernel(
    const float* __restrict__ in, bf16* __restrict__ out, int R, int Ccols) {
  __shared__ float tile[32][33];
  int c0 = blockIdx.x * 32, r0 = blockIdx.y * 32;
  int tx = threadIdx.x & 31;
  int ty = threadIdx.x >> 5;
#pragma unroll
  for (int i = 0; i < 4; ++i) {
    int r = ty + i * 8;
    tile[r][tx] = in[(size_t)(r0 + r) * Ccols + c0 + tx];
  }
  __syncthreads();
#pragma unroll
  for (int i = 0; i < 4; ++i) {
    int c = ty + i * 8;
    out[(size_t)(c0 + c) * R + r0 + tx] = (bf16)tile[tx][c];
  }
}

// ---------------------------------------------------------------------------
// Tiled bf16 transpose: out[z][c][r] = in[z][r][c].  R,C mult of 32.
// ---------------------------------------------------------------------------
__global__ __launch_bounds__(256) void transpose_bf16_kernel(
    const bf16* __restrict__ in, bf16* __restrict__ out, int R, int Ccols) {
  __shared__ bf16 tile[32][33];
  const bf16* inp = in + (size_t)blockIdx.z * R * Ccols;
  bf16* outp = out + (size_t)blockIdx.z * R * Ccols;
  int c0 = blockIdx.x * 32, r0 = blockIdx.y * 32;
  int tx = threadIdx.x & 31;
  int ty = threadIdx.x >> 5;
#pragma unroll
  for (int i = 0; i < 4; ++i) {
    int r = ty + i * 8;
    tile[r][tx] = inp[(size_t)(r0 + r) * Ccols + c0 + tx];
  }
  __syncthreads();
#pragma unroll
  for (int i = 0; i < 4; ++i) {
    int c = ty + i * 8;
    outp[(size_t)(c0 + c) * R + r0 + tx] = tile[tx][c];
  }
}

// ---------------------------------------------------------------------------
// GEMM: out[M][N] = A[M][768] * Bt[N][768]^T + bias[N]   (A,Bt bf16; bias f32)
// MODE 0: store FLOAT to outf.  MODE 1: scatter bf16 into q/k/v [b,h,t,d].
// 128x128 tile, BK=32, 4 waves, async global_load_lds staging (m97 pattern).
// (R2-proven epilogue; R3's swapped-fragment variant regressed MODE 1.)
// ---------------------------------------------------------------------------
template <int MODE>
__global__ __launch_bounds__(256) void gemm_kernel(
    const bf16* __restrict__ A, const bf16* __restrict__ Bt,
    const float* __restrict__ bias, int N, float* __restrict__ outf,
    bf16* __restrict__ qo, bf16* __restrict__ ko, bf16* __restrict__ vo) {
  constexpr int Kdim = 768;
  __shared__ __align__(16) bf16 As[128][32];
  __shared__ __align__(16) bf16 Bs[128][32];
  const int tid = threadIdx.x;
  const int lane = tid & 63;
  const int wave = tid >> 6;
  const int wm = (wave >> 1) * 64, wn = (wave & 1) * 64;
  const int m0 = blockIdx.y * 128, n0 = blockIdx.x * 128;
  const int l15 = lane & 15, q4 = lane >> 4;

  f32x4 acc[4][4] = {};

  const int ca = wave * 2;
  const int ar = lane >> 2;
  const int ac = (lane & 3) * 8;
  bf16* asBase = &As[0][0];
  bf16* bsBase = &Bs[0][0];

  for (int k0 = 0; k0 < Kdim; k0 += 32) {
    const bf16* gA = A + (size_t)(m0 + ca * 16 + ar) * Kdim + k0 + ac;
    async16(gA, asBase + ca * 512);
    async16(gA + 16 * Kdim, asBase + (ca + 1) * 512);
    const bf16* gB = Bt + (size_t)(n0 + ca * 16 + ar) * Kdim + k0 + ac;
    async16(gB, bsBase + ca * 512);
    async16(gB + 16 * Kdim, bsBase + (ca + 1) * 512);
    __syncthreads();
    bf16x8v af[4], bfg[4];
#pragma unroll
    for (int i = 0; i < 4; ++i)
      af[i] = *(const bf16x8v*)&As[wm + i * 16 + l15][q4 * 8];
#pragma unroll
    for (int i = 0; i < 4; ++i)
      bfg[i] = *(const bf16x8v*)&Bs[wn + i * 16 + l15][q4 * 8];
#pragma unroll
    for (int mi = 0; mi < 4; ++mi)
#pragma unroll
      for (int ni = 0; ni < 4; ++ni)
        acc[mi][ni] = MFMA_BF16(af[mi], bfg[ni], acc[mi][ni]);
    __syncthreads();
  }

#pragma unroll
  for (int mi = 0; mi < 4; ++mi) {
#pragma unroll
    for (int ni = 0; ni < 4; ++ni) {
      int col = n0 + wn + ni * 16 + l15;
      float bv = bias[col];
#pragma unroll
      for (int r = 0; r < 4; ++r) {
        int row = m0 + wm + mi * 16 + q4 * 4 + r;
        float val = acc[mi][ni][r] + bv;
        if (MODE == 0) {
          outf[(size_t)row * N + col] = val;
        } else {
          int sel = col / 768;
          int cc = col - sel * 768;
          int h = cc >> 6, d = cc & 63;
          int b = row >> 12, t = row & 4095;
          bf16* dst = sel == 0 ? qo : (sel == 1 ? ko : vo);
          dst[((size_t)(b * 12 + h) * 4096 + t) * 64 + d] = (bf16)val;
        }
      }
    }
  }
}

// ---------------------------------------------------------------------------
// Flash attention (causal), fixed-max exp2 softmax, rowsum via MFMA, async
// TRIPLE-buffered swizzled staging with COUNTED vmcnt (T4).
//
// Mirror-pair block: q-tiles {63-p, p}; ONE staged K/V stream of 64-p tiles
// serves both.  8 waves, one 16-row strip per wave (waves 0-3 big tile,
// 4-7 small tile; R6-proven, occupancy-neutral 12..24 waves/CU).
//
// PIPELINE (replaces __syncthreads drain — R6 diagnosis: per-pipe totals
// sum to ~55-60% of measured cycles; the gap is the per-iter full
// vmcnt(0)+lgkmcnt(0) drain at each barrier):
//   prologue: stage(0), stage(1)
//   iter kt:  s_waitcnt vmcnt(2)   <- tile kt's 2 loads done; kt+1's stay
//             s_barrier               in flight ACROSS the barrier
//             stage(kt+2, (kt+2)%3) <- buffer freed by this barrier (all
//             compute tile kt          waves finished it at iter kt-1)
// vmcnt completion is FIFO, so vmcnt(2) retires exactly the oldest pair.
// Last iter waits vmcnt(0) (nothing newer in flight).
//
// p MAP (R2-proven, do not change): bh = id%24, p = id/24.  24 = 0 mod 8 ->
// all 32 blocks of one bh land on ONE XCD -> its L2 holds 3 heads' K/V.
// (R3's remap broke this: FETCH 18.5MB -> 102MB.)
//
// QK^T SWAPPED (mfma(K,Q)): lane (q4,l15) holds S[qrow=l15][key=16ni+4q4+r].
// P -> LDS via 4 ds_write_b64; swizzled ds_read_b128 yields the PV A-frag
// (proven path; permlane in-register variant failed twice, R1/R5).
// 64 KB LDS -> 2 blocks/CU, __launch_bounds__(512,4) = 16 waves/CU.
// ---------------------------------------------------------------------------
__global__ __launch_bounds__(512, 4) void attn_kernel(
    const bf16* __restrict__ q, const bf16* __restrict__ k,
    const bf16* __restrict__ vt, bf16* __restrict__ y) {
  __shared__ __align__(16) bf16 Kb[3][64][64];  // [key][d], swizzled
  __shared__ __align__(16) bf16 Vb[3][64][64];  // [d][key], swizzled
  __shared__ __align__(16) bf16 Ps[8][16][64];  // per-wave P, swizzled
  const int tid = threadIdx.x;
  const int lane = tid & 63, wave = tid >> 6;  // wave 0..7
  const int l15 = lane & 15, q4 = lane >> 4;
  const int swz = l15 & 7;
  const int id = blockIdx.x;
  const int bh = id % 24;
  const int p = id / 24;  // 0..31
  // wave role: one 16-row strip.  waves 0-3: big tile 63-p; 4-7: small tile p
  const int rs = (wave < 4) ? ((63 - p) * 64 + wave * 16)
                            : (p * 64 + (wave - 4) * 16);
  const int hb = bh % 12, bb = bh / 12;

  // staging geometry: one async16 wave-call covers 8 rows x 8 chunks (1 KB);
  // each of 8 waves stages one 8-row group of K and of V.
  const int gr = lane >> 3;        // row within 8-row group
  const int sj = (lane & 7) ^ gr;  // global source chunk (XOR swizzle)
  const bf16* kgbase = k + (size_t)bh * 4096 * 64;
  const bf16* vgbase = vt + (size_t)bh * 64 * 4096;

  bf16x8v ones;
#pragma unroll
  for (int j = 0; j < 8; ++j) ones[j] = (bf16)1.0f;

  // Q fragments for this wave's strip, pre-scaled by log2(e)/sqrt(64)
  bf16x8v qf[2];
  {
    const bf16* qrow = q + ((size_t)bh * 4096 + rs + l15) * 64 + q4 * 8;
#pragma unroll
    for (int ks = 0; ks < 2; ++ks) {
      bf16x8v t8 = *(const bf16x8v*)(qrow + ks * 32);
#pragma unroll
      for (int j = 0; j < 8; ++j) t8[j] = (bf16)((float)t8[j] * 0.18033688f);
      qf[ks] = t8;
    }
  }

  f32x4 o[4] = {};
  f32x4 ol = {};

  auto stage = [&](int kt, int buf) {
    const int t0k = kt * 64;
    async16(kgbase + (size_t)(t0k + wave * 8 + gr) * 64 + sj * 8,
            &Kb[buf][wave * 8][0]);
    async16(vgbase + (size_t)(wave * 8 + gr) * 4096 + t0k + sj * 8,
            &Vb[buf][wave * 8][0]);
  };

  // p = exp2(s - 28.854); full (no mask) variant
  auto sm_full = [&](f32x4 (&s)[4]) {
#pragma unroll
    for (int ni = 0; ni < 4; ++ni)
#pragma unroll
      for (int r = 0; r < 4; ++r)
        s[ni][r] = __builtin_amdgcn_exp2f(s[ni][r] - 28.8539008f);
  };
  // masked variant: local key (ni*16+q4*4+r) valid iff <= lim
  auto sm_mask = [&](f32x4 (&s)[4], int lim) {
#pragma unroll
    for (int ni = 0; ni < 4; ++ni)
#pragma unroll
      for (int r = 0; r < 4; ++r)
        s[ni][r] = (ni * 16 + q4 * 4 + r <= lim)
                       ? __builtin_amdgcn_exp2f(s[ni][r] - 28.8539008f)
                       : 0.0f;
  };
  // P row write: lane (q4,l15) owns keys ni*16 + q4*4 + {0..3} of q-row l15.
  auto pwrite = [&](const f32x4 (&s)[4]) {
#pragma unroll
    for (int ni = 0; ni < 4; ++ni) {
      bf16x4v pv4;
#pragma unroll
      for (int e = 0; e < 4; ++e) pv4[e] = (bf16)s[ni][e];
      const int jb = ni * 2 + (q4 >> 1);
      *(bf16x4v*)&Ps[wave][l15][((jb ^ (l15 & 7)) * 8) + (q4 & 1) * 4] = pv4;
    }
  };

  const int ktmax = 64 - p;  // tiles needed by the big tile (>= 33)
  stage(0, 0);
  stage(1, 1);  // ktmax >= 33, tile 1 always exists

  for (int kt = 0; kt < ktmax; ++kt) {
    const int buf = kt % 3;
    // counted wait: retire the oldest 2 loads (tile kt); tile kt+1's 2
    // loads remain in flight across the barrier (never drain in-loop).
    if (kt + 1 < ktmax)
      asm volatile("s_waitcnt vmcnt(2)" ::: "memory");
    else
      asm volatile("s_waitcnt vmcnt(0)" ::: "memory");
    __builtin_amdgcn_s_barrier();
    // buffer (kt+2)%3 == (kt-1)%3 was fully consumed at iter kt-1; the
    // barrier above proves all waves have passed that point.
    if (kt + 2 < ktmax) stage(kt + 2, (kt + 2) % 3);
    const int t0 = kt * 64;

    if (t0 <= rs + 15) {  // wave-uniform: this strip still has work
      // S^T = K Q^T (exp2 domain)
      // Lane (q4,l15): s[ni][r] = S[qrow = rs + l15][key = t0+ni*16+q4*4+r]
      f32x4 s[4] = {};
      __builtin_amdgcn_s_setprio(1);
#pragma unroll
      for (int ni = 0; ni < 4; ++ni) {
#pragma unroll
        for (int ks = 0; ks < 2; ++ks) {
          bf16x8v kf = *(const bf16x8v*)&Kb[buf][ni * 16 + l15]
                                           [((ks * 4 + q4) ^ swz) * 8];
          s[ni] = MFMA_BF16(kf, qf[ks], s[ni]);
        }
      }
      __builtin_amdgcn_s_setprio(0);

      // softmax + P write (masked only near the diagonal)
      if (t0 + 63 <= rs) sm_full(s); else sm_mask(s, rs + l15 - t0);
      pwrite(s);

      // PV A-frag: proven swizzled b128 read path (row = q_row = l15)
      bf16x8v pf[2];
#pragma unroll
      for (int ks = 0; ks < 2; ++ks)
        pf[ks] = *(const bf16x8v*)&Ps[wave][l15][((ks * 4 + q4) ^ swz) * 8];

      // O += P V ; rowsum l += P * ones
      __builtin_amdgcn_s_setprio(1);
#pragma unroll
      for (int d4 = 0; d4 < 4; ++d4) {
#pragma unroll
        for (int ks = 0; ks < 2; ++ks) {
          bf16x8v vf = *(const bf16x8v*)&Vb[buf][d4 * 16 + l15]
                                           [((ks * 4 + q4) ^ swz) * 8];
          o[d4] = MFMA_BF16(pf[ks], vf, o[d4]);
        }
      }
#pragma unroll
      for (int ks = 0; ks < 2; ++ks) ol = MFMA_BF16(pf[ks], ones, ol);
      __builtin_amdgcn_s_setprio(0);
    }
  }

  // epilogue: y[b][t][h*64+d] = O / l  (fixed-max scale cancels)
  // PV output D-layout: q_row = rs + q4*4 + r, d = d4*16 + l15.
#pragma unroll
  for (int d4 = 0; d4 < 4; ++d4)
#pragma unroll
    for (int r = 0; r < 4; ++r) {
      int row = rs + q4 * 4 + r;
      y[((size_t)(bb * 4096 + row)) * 768 + hb * 64 + d4 * 16 + l15] =
          (bf16)(o[d4][r] / ol[r]);
    }
}

// ---------------------------------------------------------------------------
extern "C" void kernel_launch(void* const* d_in, const int* in_sizes, int n_in,
                              void* d_out, int out_size, void* d_ws,
                              size_t ws_size, hipStream_t stream) {
  const float* x = (const float*)d_in[0];       // (2,4096,768) f32
  const float* w_attn = (const float*)d_in[1];  // (768,2304) f32
  const float* b_attn = (const float*)d_in[2];  // (2304) f32
  const float* w_proj = (const float*)d_in[3];  // (768,768) f32
  const float* b_proj = (const float*)d_in[4];  // (768) f32
  float* out = (float*)d_out;                   // (8192*768) f32

  char* ws = (char*)d_ws;
  size_t off = 0;
  auto carve = [&](size_t elems) {
    char* p = ws + off;
    off += ((elems * sizeof(bf16) + 255) & ~(size_t)255);
    return (bf16*)p;
  };
  bf16* xb = carve((size_t)8192 * 768);      // x bf16; reused as vtb
  bf16* wt_attn = carve((size_t)2304 * 768);
  bf16* wt_proj = carve((size_t)768 * 768);
  bf16* qb = carve((size_t)24 * 4096 * 64);
  bf16* kb = carve((size_t)24 * 4096 * 64);
  bf16* vb = carve((size_t)24 * 4096 * 64);  // reused as yb
  bf16* vtb = xb;  // xb dead after QKV gemm
  bf16* yb = vb;   // vb dead after V transpose

  convert_kernel<<<(8192 * 768 / 8 + 255) / 256, 256, 0, stream>>>(
      x, xb, 8192 * 768 / 8);
  transpose_conv_kernel<<<dim3(2304 / 32, 768 / 32), 256, 0, stream>>>(
      w_attn, wt_attn, 768, 2304);
  transpose_conv_kernel<<<dim3(768 / 32, 768 / 32), 256, 0, stream>>>(
      w_proj, wt_proj, 768, 768);
  gemm_kernel<1><<<dim3(2304 / 128, 8192 / 128), 256, 0, stream>>>(
      xb, wt_attn, b_attn, 2304, nullptr, qb, kb, vb);
  transpose_bf16_kernel<<<dim3(64 / 32, 4096 / 32, 24), 256, 0, stream>>>(
      vb, vtb, 4096, 64);
  attn_kernel<<<dim3(768), 512, 0, stream>>>(qb, kb, vtb, yb);
  gemm_kernel<0><<<dim3(768 / 128, 8192 / 128), 256, 0, stream>>>(
      yb, wt_proj, b_proj, 768, out, nullptr, nullptr, nullptr);
}

// Round 8
// 248.320 us; speedup vs baseline: 1.0545x; 1.0545x over previous
//
#include <hip/hip_runtime.h>

typedef __bf16 bf16;
typedef float f32x4 __attribute__((ext_vector_type(4)));
typedef bf16 bf16x8v __attribute__((ext_vector_type(8)));
typedef bf16 bf16x4v __attribute__((ext_vector_type(4)));

#define MFMA_BF16(a, b, c) __builtin_amdgcn_mfma_f32_16x16x32_bf16((a), (b), (c), 0, 0, 0)

// async global->LDS, 16B per lane (dest = wave-uniform base + lane*16)
__device__ __forceinline__ void async16(const bf16* g, bf16* l) {
  __builtin_amdgcn_global_load_lds(
      (const __attribute__((address_space(1))) void*)g,
      (__attribute__((address_space(3))) void*)l, 16, 0, 0);
}

// ---------------------------------------------------------------------------
// f32 -> bf16 convert, 8 elements/thread.
// ---------------------------------------------------------------------------
__global__ __launch_bounds__(256) void convert_kernel(
    const float* __restrict__ in, bf16* __restrict__ out, int n8) {
  int i = blockIdx.x * 256 + threadIdx.x;
  if (i >= n8) return;
  const float4* p = (const float4*)in + (size_t)i * 2;
  float4 a = p[0], b = p[1];
  bf16x8v o;
  o[0] = (bf16)a.x; o[1] = (bf16)a.y; o[2] = (bf16)a.z; o[3] = (bf16)a.w;
  o[4] = (bf16)b.x; o[5] = (bf16)b.y; o[6] = (bf16)b.z; o[7] = (bf16)b.w;
  ((bf16x8v*)out)[i] = o;
}

// ---------------------------------------------------------------------------
// Tiled transpose + f32->bf16: out[c][r] = (bf16)in[r][c].  R,C mult of 32.
// ---------------------------------------------------------------------------
__global__ __launch_bounds__(256) void transpose_conv_kernel(
    const float* __restrict__ in, bf16* __restrict__ out, int R, int Ccols) {
  __shared__ float tile[32][33];
  int c0 = blockIdx.x * 32, r0 = blockIdx.y * 32;
  int tx = threadIdx.x & 31;
  int ty = threadIdx.x >> 5;
#pragma unroll
  for (int i = 0; i < 4; ++i) {
    int r = ty + i * 8;
    tile[r][tx] = in[(size_t)(r0 + r) * Ccols + c0 + tx];
  }
  __syncthreads();
#pragma unroll
  for (int i = 0; i < 4; ++i) {
    int c = ty + i * 8;
    out[(size_t)(c0 + c) * R + r0 + tx] = (bf16)tile[tx][c];
  }
}

// ---------------------------------------------------------------------------
// Tiled bf16 transpose: out[z][c][r] = in[z][r][c].  R,C mult of 32.
// ---------------------------------------------------------------------------
__global__ __launch_bounds__(256) void transpose_bf16_kernel(
    const bf16* __restrict__ in, bf16* __restrict__ out, int R, int Ccols) {
  __shared__ bf16 tile[32][33];
  const bf16* inp = in + (size_t)blockIdx.z * R * Ccols;
  bf16* outp = out + (size_t)blockIdx.z * R * Ccols;
  int c0 = blockIdx.x * 32, r0 = blockIdx.y * 32;
  int tx = threadIdx.x & 31;
  int ty = threadIdx.x >> 5;
#pragma unroll
  for (int i = 0; i < 4; ++i) {
    int r = ty + i * 8;
    tile[r][tx] = inp[(size_t)(r0 + r) * Ccols + c0 + tx];
  }
  __syncthreads();
#pragma unroll
  for (int i = 0; i < 4; ++i) {
    int c = ty + i * 8;
    outp[(size_t)(c0 + c) * R + r0 + tx] = tile[tx][c];
  }
}

// ---------------------------------------------------------------------------
// GEMM: out[M][N] = A[M][768] * Bt[N][768]^T + bias[N]   (A,Bt bf16; bias f32)
// MODE 0: store FLOAT to outf.  MODE 1: scatter bf16 into q/k/v [b,h,t,d].
// 128x128 tile, BK=32, 4 waves, async global_load_lds staging (m97 pattern).
// ---------------------------------------------------------------------------
template <int MODE>
__global__ __launch_bounds__(256) void gemm_kernel(
    const bf16* __restrict__ A, const bf16* __restrict__ Bt,
    const float* __restrict__ bias, int N, float* __restrict__ outf,
    bf16* __restrict__ qo, bf16* __restrict__ ko, bf16* __restrict__ vo) {
  constexpr int Kdim = 768;
  __shared__ __align__(16) bf16 As[128][32];
  __shared__ __align__(16) bf16 Bs[128][32];
  const int tid = threadIdx.x;
  const int lane = tid & 63;
  const int wave = tid >> 6;
  const int wm = (wave >> 1) * 64, wn = (wave & 1) * 64;
  const int m0 = blockIdx.y * 128, n0 = blockIdx.x * 128;
  const int l15 = lane & 15, q4 = lane >> 4;

  f32x4 acc[4][4] = {};

  const int ca = wave * 2;
  const int ar = lane >> 2;
  const int ac = (lane & 3) * 8;
  bf16* asBase = &As[0][0];
  bf16* bsBase = &Bs[0][0];

  for (int k0 = 0; k0 < Kdim; k0 += 32) {
    const bf16* gA = A + (size_t)(m0 + ca * 16 + ar) * Kdim + k0 + ac;
    async16(gA, asBase + ca * 512);
    async16(gA + 16 * Kdim, asBase + (ca + 1) * 512);
    const bf16* gB = Bt + (size_t)(n0 + ca * 16 + ar) * Kdim + k0 + ac;
    async16(gB, bsBase + ca * 512);
    async16(gB + 16 * Kdim, bsBase + (ca + 1) * 512);
    __syncthreads();
    bf16x8v af[4], bfg[4];
#pragma unroll
    for (int i = 0; i < 4; ++i)
      af[i] = *(const bf16x8v*)&As[wm + i * 16 + l15][q4 * 8];
#pragma unroll
    for (int i = 0; i < 4; ++i)
      bfg[i] = *(const bf16x8v*)&Bs[wn + i * 16 + l15][q4 * 8];
#pragma unroll
    for (int mi = 0; mi < 4; ++mi)
#pragma unroll
      for (int ni = 0; ni < 4; ++ni)
        acc[mi][ni] = MFMA_BF16(af[mi], bfg[ni], acc[mi][ni]);
    __syncthreads();
  }

#pragma unroll
  for (int mi = 0; mi < 4; ++mi) {
#pragma unroll
    for (int ni = 0; ni < 4; ++ni) {
      int col = n0 + wn + ni * 16 + l15;
      float bv = bias[col];
#pragma unroll
      for (int r = 0; r < 4; ++r) {
        int row = m0 + wm + mi * 16 + q4 * 4 + r;
        float val = acc[mi][ni][r] + bv;
        if (MODE == 0) {
          outf[(size_t)row * N + col] = val;
        } else {
          int sel = col / 768;
          int cc = col - sel * 768;
          int h = cc >> 6, d = cc & 63;
          int b = row >> 12, t = row & 4095;
          bf16* dst = sel == 0 ? qo : (sel == 1 ? ko : vo);
          dst[((size_t)(b * 12 + h) * 4096 + t) * 64 + d] = (bf16)val;
        }
      }
    }
  }
}

// ---------------------------------------------------------------------------
// Flash attention (causal), fixed-max exp2 softmax, rowsum via MFMA, async
// double-buffered swizzled staging (__syncthreads dbuf — R7's counted-vmcnt
// triple-buffer regressed 27%: asm-pinned order defeats compiler scheduling).
//
// LDS-PIPE ROOFLINE (R6 diagnosis): per 16-row strip-iter a wave issued
// 18 ds_read_b128 + 4 ds_write_b64 ~ 240 LDS cycles; 780 strip-iters/CU
// x 240 + staging ~ 86 us = measured.  Fix: SAME-TILE STRIP PAIRING —
// each wave owns TWO strips (32 q-rows) of ONE tile, so the 8 kf + 8 vf
// reads are shared by both strips' MFMAs (R2-proven dual s0/s1 code):
// 288 cyc / 2 strips = 144/strip (-40%).  Same-tile strips are ALWAYS
// co-active (unlike R2's mirror-tile pairing: shared only while small
// tile live).  New roofline ~51 us LDS, ~40 us VALU.
//
// Mirror-pair block: q-tiles {63-p, p}; waves 0,1 = big tile rows 0-31 /
// 32-63; waves 2,3 = small tile (idle at barriers past kt > p; R6 showed
// this imbalance is worth <= 2 us).  ONE staged K/V stream serves both.
//
// p MAP (R2-proven, keep): bh = id%24, p = id/24.  24 = 0 mod 8 -> all 32
// blocks of one bh land on ONE XCD -> its L2 holds 3 heads' K/V (FETCH
// 18.5MB; R3's remap broke it to 102MB).
//
// QK^T SWAPPED (mfma(K,Q)): lane (q4,l15) holds S^T[key=16ni+4q4+r][qrow=
// l15].  P -> LDS via 4 ds_write_b64/strip; swizzled ds_read_b128 PV A-frag
// (proven path; in-register permlane variant failed twice, R1/R5).
// 48 KB LDS -> 3 blocks/CU = 12 waves/CU.
// ---------------------------------------------------------------------------
__global__ __launch_bounds__(256, 3) void attn_kernel(
    const bf16* __restrict__ q, const bf16* __restrict__ k,
    const bf16* __restrict__ vt, bf16* __restrict__ y) {
  __shared__ __align__(16) bf16 Kb[2][64][64];  // [key][d], swizzled
  __shared__ __align__(16) bf16 Vb[2][64][64];  // [d][key], swizzled
  __shared__ __align__(16) bf16 Ps[4][32][64];  // per-wave P (2 strips), swz
  const int tid = threadIdx.x;
  const int lane = tid & 63, wave = tid >> 6;  // wave 0..3
  const int l15 = lane & 15, q4 = lane >> 4;
  const int swz = l15 & 7;
  const int id = blockIdx.x;
  const int bh = id % 24;
  const int p = id / 24;  // 0..31
  // wave role: 32 rows of one tile.  waves 0,1: big tile 63-p; 2,3: small p
  const int tb = (wave < 2) ? (63 - p) * 64 : p * 64;
  const int rs0 = tb + (wave & 1) * 32;  // strip0 rows rs0..rs0+15
  const int rs1 = rs0 + 16;              // strip1 rows rs1..rs1+15
  const int hb = bh % 12, bb = bh / 12;

  // staging geometry: one async16 wave-call covers 8 rows x 8 chunks (1 KB)
  const int gr = lane >> 3;        // row within 8-row group
  const int sj = (lane & 7) ^ gr;  // global source chunk (XOR swizzle)
  const bf16* kgbase = k + (size_t)bh * 4096 * 64;
  const bf16* vgbase = vt + (size_t)bh * 64 * 4096;

  bf16x8v ones;
#pragma unroll
  for (int j = 0; j < 8; ++j) ones[j] = (bf16)1.0f;

  // Q fragments (both strips), pre-scaled by log2(e)/sqrt(64)
  bf16x8v qf[2][2];
#pragma unroll
  for (int st = 0; st < 2; ++st) {
    const int rs = st ? rs1 : rs0;
    const bf16* qrow = q + ((size_t)bh * 4096 + rs + l15) * 64 + q4 * 8;
#pragma unroll
    for (int ks = 0; ks < 2; ++ks) {
      bf16x8v t8 = *(const bf16x8v*)(qrow + ks * 32);
#pragma unroll
      for (int j = 0; j < 8; ++j) t8[j] = (bf16)((float)t8[j] * 0.18033688f);
      qf[st][ks] = t8;
    }
  }

  f32x4 o0[4] = {}, o1[4] = {};
  f32x4 ol0 = {}, ol1 = {};

  auto stage = [&](int kt, int buf) {
    const int t0k = kt * 64;
#pragma unroll
    for (int g = 0; g < 2; ++g) {
      const int grp = wave * 2 + g;  // 8-row group 0..7
      async16(kgbase + (size_t)(t0k + grp * 8 + gr) * 64 + sj * 8,
              &Kb[buf][grp * 8][0]);
      async16(vgbase + (size_t)(grp * 8 + gr) * 4096 + t0k + sj * 8,
              &Vb[buf][grp * 8][0]);
    }
  };

  // p = exp2(s - 28.854); full (no mask) variant
  auto sm_full = [&](f32x4 (&s)[4]) {
#pragma unroll
    for (int ni = 0; ni < 4; ++ni)
#pragma unroll
      for (int r = 0; r < 4; ++r)
        s[ni][r] = __builtin_amdgcn_exp2f(s[ni][r] - 28.8539008f);
  };
  // masked variant: local key (ni*16+q4*4+r) valid iff <= lim
  auto sm_mask = [&](f32x4 (&s)[4], int lim) {
#pragma unroll
    for (int ni = 0; ni < 4; ++ni)
#pragma unroll
      for (int r = 0; r < 4; ++r)
        s[ni][r] = (ni * 16 + q4 * 4 + r <= lim)
                       ? __builtin_amdgcn_exp2f(s[ni][r] - 28.8539008f)
                       : 0.0f;
  };
  // P row write: lane (q4,l15) owns keys ni*16 + q4*4 + {0..3} of q-row l15.
  auto pwrite = [&](const f32x4 (&s)[4], int row) {
#pragma unroll
    for (int ni = 0; ni < 4; ++ni) {
      bf16x4v pv4;
#pragma unroll
      for (int e = 0; e < 4; ++e) pv4[e] = (bf16)s[ni][e];
      const int jb = ni * 2 + (q4 >> 1);
      *(bf16x4v*)&Ps[wave][row][((jb ^ (row & 7)) * 8) + (q4 & 1) * 4] = pv4;
    }
  };

  const int ktmax = 64 - p;  // tiles needed by the big tile
  stage(0, 0);

  for (int kt = 0; kt < ktmax; ++kt) {
    const int buf = kt & 1;
    __syncthreads();  // drains vmcnt: tile kt resident; buf^1 free
    if (kt + 1 < ktmax) stage(kt + 1, buf ^ 1);
    const int t0 = kt * 64;

    if (t0 <= rs1 + 15) {  // wave-uniform: this wave's 32 rows still active
      // S^T = K Q^T (exp2 domain); BOTH strips share every kf read.
      // Lane (q4,l15): s{st}[ni][r] = S[qrow=rs{st}+l15][key=t0+16ni+4q4+r]
      f32x4 s0[4] = {}, s1[4] = {};
      __builtin_amdgcn_s_setprio(1);
#pragma unroll
      for (int ni = 0; ni < 4; ++ni) {
#pragma unroll
        for (int ks = 0; ks < 2; ++ks) {
          bf16x8v kf = *(const bf16x8v*)&Kb[buf][ni * 16 + l15]
                                           [((ks * 4 + q4) ^ swz) * 8];
          s0[ni] = MFMA_BF16(kf, qf[0][ks], s0[ni]);
          s1[ni] = MFMA_BF16(kf, qf[1][ks], s1[ni]);
        }
      }
      __builtin_amdgcn_s_setprio(0);

      // softmax + P writes (strip0 -> Ps rows 0..15, strip1 -> 16..31)
      if (t0 + 63 <= rs0) sm_full(s0); else sm_mask(s0, rs0 + l15 - t0);
      pwrite(s0, l15);
      if (t0 + 63 <= rs1) sm_full(s1); else sm_mask(s1, rs1 + l15 - t0);
      pwrite(s1, 16 + l15);

      // PV A-frags: proven swizzled b128 read path (row = q_row)
      bf16x8v pf0[2], pf1[2];
#pragma unroll
      for (int ks = 0; ks < 2; ++ks) {
        pf0[ks] = *(const bf16x8v*)&Ps[wave][l15][((ks * 4 + q4) ^ swz) * 8];
        pf1[ks] =
            *(const bf16x8v*)&Ps[wave][16 + l15][((ks * 4 + q4) ^ swz) * 8];
      }

      // O += P V ; rowsum l += P * ones  (both strips share every vf read)
      __builtin_amdgcn_s_setprio(1);
#pragma unroll
      for (int d4 = 0; d4 < 4; ++d4) {
#pragma unroll
        for (int ks = 0; ks < 2; ++ks) {
          bf16x8v vf = *(const bf16x8v*)&Vb[buf][d4 * 16 + l15]
                                           [((ks * 4 + q4) ^ swz) * 8];
          o0[d4] = MFMA_BF16(pf0[ks], vf, o0[d4]);
          o1[d4] = MFMA_BF16(pf1[ks], vf, o1[d4]);
        }
      }
#pragma unroll
      for (int ks = 0; ks < 2; ++ks) {
        ol0 = MFMA_BF16(pf0[ks], ones, ol0);
        ol1 = MFMA_BF16(pf1[ks], ones, ol1);
      }
      __builtin_amdgcn_s_setprio(0);
    }
  }

  // epilogue: y[b][t][h*64+d] = O / l  (fixed-max scale cancels)
  // PV output D-layout: q_row = rs + q4*4 + r, d = d4*16 + l15.
#pragma unroll
  for (int d4 = 0; d4 < 4; ++d4)
#pragma unroll
    for (int r = 0; r < 4; ++r) {
      int row0 = rs0 + q4 * 4 + r;
      y[((size_t)(bb * 4096 + row0)) * 768 + hb * 64 + d4 * 16 + l15] =
          (bf16)(o0[d4][r] / ol0[r]);
      int row1 = rs1 + q4 * 4 + r;
      y[((size_t)(bb * 4096 + row1)) * 768 + hb * 64 + d4 * 16 + l15] =
          (bf16)(o1[d4][r] / ol1[r]);
    }
}

// ---------------------------------------------------------------------------
extern "C" void kernel_launch(void* const* d_in, const int* in_sizes, int n_in,
                              void* d_out, int out_size, void* d_ws,
                              size_t ws_size, hipStream_t stream) {
  const float* x = (const float*)d_in[0];       // (2,4096,768) f32
  const float* w_attn = (const float*)d_in[1];  // (768,2304) f32
  const float* b_attn = (const float*)d_in[2];  // (2304) f32
  const float* w_proj = (const float*)d_in[3];  // (768,768) f32
  const float* b_proj = (const float*)d_in[4];  // (768) f32
  float* out = (float*)d_out;                   // (8192*768) f32

  char* ws = (char*)d_ws;
  size_t off = 0;
  auto carve = [&](size_t elems) {
    char* p = ws + off;
    off += ((elems * sizeof(bf16) + 255) & ~(size_t)255);
    return (bf16*)p;
  };
  bf16* xb = carve((size_t)8192 * 768);      // x bf16; reused as vtb
  bf16* wt_attn = carve((size_t)2304 * 768);
  bf16* wt_proj = carve((size_t)768 * 768);
  bf16* qb = carve((size_t)24 * 4096 * 64);
  bf16* kb = carve((size_t)24 * 4096 * 64);
  bf16* vb = carve((size_t)24 * 4096 * 64);  // reused as yb
  bf16* vtb = xb;  // xb dead after QKV gemm
  bf16* yb = vb;   // vb dead after V transpose

  convert_kernel<<<(8192 * 768 / 8 + 255) / 256, 256, 0, stream>>>(
      x, xb, 8192 * 768 / 8);
  transpose_conv_kernel<<<dim3(2304 / 32, 768 / 32), 256, 0, stream>>>(
      w_attn, wt_attn, 768, 2304);
  transpose_conv_kernel<<<dim3(768 / 32, 768 / 32), 256, 0, stream>>>(
      w_proj, wt_proj, 768, 768);
  gemm_kernel<1><<<dim3(2304 / 128, 8192 / 128), 256, 0, stream>>>(
      xb, wt_attn, b_attn, 2304, nullptr, qb, kb, vb);
  transpose_bf16_kernel<<<dim3(64 / 32, 4096 / 32, 24), 256, 0, stream>>>(
      vb, vtb, 4096, 64);
  attn_kernel<<<dim3(768), 256, 0, stream>>>(qb, kb, vtb, yb);
  gemm_kernel<0><<<dim3(768 / 128, 8192 / 128), 256, 0, stream>>>(
      yb, wt_proj, b_proj, 768, out, nullptr, nullptr, nullptr);
}

// Round 9
// 236.628 us; speedup vs baseline: 1.1066x; 1.0494x over previous
//
#include <hip/hip_runtime.h>

typedef __bf16 bf16;
typedef float f32x4 __attribute__((ext_vector_type(4)));
typedef bf16 bf16x8v __attribute__((ext_vector_type(8)));
typedef bf16 bf16x4v __attribute__((ext_vector_type(4)));

#define MFMA_BF16(a, b, c) __builtin_amdgcn_mfma_f32_16x16x32_bf16((a), (b), (c), 0, 0, 0)

// async global->LDS, 16B per lane (dest = wave-uniform base + lane*16)
__device__ __forceinline__ void async16(const bf16* g, bf16* l) {
  __builtin_amdgcn_global_load_lds(
      (const __attribute__((address_space(1))) void*)g,
      (__attribute__((address_space(3))) void*)l, 16, 0, 0);
}

// ---------------------------------------------------------------------------
// Fused prep: f32->bf16 convert of x  +  two transpose+convert of weights.
// Blocks 0..3071: convert (8 elems/thread).  3072..4799: w_attn transpose.
// 4800..5375: w_proj transpose.  Saves 2 kernel launches.
// ---------------------------------------------------------------------------
__global__ __launch_bounds__(256) void prep_kernel(
    const float* __restrict__ x, bf16* __restrict__ xb,
    const float* __restrict__ w_attn, bf16* __restrict__ wt_attn,
    const float* __restrict__ w_proj, bf16* __restrict__ wt_proj) {
  __shared__ float tile[32][33];
  const int b = blockIdx.x;
  if (b < 3072) {
    int i = b * 256 + threadIdx.x;
    const float4* p = (const float4*)x + (size_t)i * 2;
    float4 a = p[0], c = p[1];
    bf16x8v o;
    o[0] = (bf16)a.x; o[1] = (bf16)a.y; o[2] = (bf16)a.z; o[3] = (bf16)a.w;
    o[4] = (bf16)c.x; o[5] = (bf16)c.y; o[6] = (bf16)c.z; o[7] = (bf16)c.w;
    ((bf16x8v*)xb)[i] = o;
    return;
  }
  const float* in;
  bf16* out;
  int Ccols, bidx;
  if (b < 4800) {
    in = w_attn; out = wt_attn; Ccols = 2304; bidx = b - 3072;
  } else {
    in = w_proj; out = wt_proj; Ccols = 768; bidx = b - 4800;
  }
  const int R = 768;
  const int gx = Ccols / 32;
  const int c0 = (bidx % gx) * 32, r0 = (bidx / gx) * 32;
  const int tx = threadIdx.x & 31;
  const int ty = threadIdx.x >> 5;
#pragma unroll
  for (int i = 0; i < 4; ++i) {
    int r = ty + i * 8;
    tile[r][tx] = in[(size_t)(r0 + r) * Ccols + c0 + tx];
  }
  __syncthreads();
#pragma unroll
  for (int i = 0; i < 4; ++i) {
    int c = ty + i * 8;
    out[(size_t)(c0 + c) * R + r0 + tx] = (bf16)tile[tx][c];
  }
}

// ---------------------------------------------------------------------------
// Tiled bf16 transpose: out[z][c][r] = in[z][r][c].  R,C mult of 32.
// ---------------------------------------------------------------------------
__global__ __launch_bounds__(256) void transpose_bf16_kernel(
    const bf16* __restrict__ in, bf16* __restrict__ out, int R, int Ccols) {
  __shared__ bf16 tile[32][33];
  const bf16* inp = in + (size_t)blockIdx.z * R * Ccols;
  bf16* outp = out + (size_t)blockIdx.z * R * Ccols;
  int c0 = blockIdx.x * 32, r0 = blockIdx.y * 32;
  int tx = threadIdx.x & 31;
  int ty = threadIdx.x >> 5;
#pragma unroll
  for (int i = 0; i < 4; ++i) {
    int r = ty + i * 8;
    tile[r][tx] = inp[(size_t)(r0 + r) * Ccols + c0 + tx];
  }
  __syncthreads();
#pragma unroll
  for (int i = 0; i < 4; ++i) {
    int c = ty + i * 8;
    outp[(size_t)(c0 + c) * R + r0 + tx] = tile[tx][c];
  }
}

// ---------------------------------------------------------------------------
// GEMM: out[M][N] = A[M][768] * Bt[N][768]^T + bias[N]   (A,Bt bf16; bias f32)
// MODE 0: store FLOAT to outf.  MODE 1: scatter bf16 into q/k/v [b,h,t,d].
// 128x128 tile, BK=64 (12 K-iters, half the barriers of BK=32), 4 waves,
// async global_load_lds staging with the attn-proven XOR swizzle:
//   source chunk sj=(lane&7)^gr  ->  LDS[row][chunk] = global[row][chunk^gr]
//   read global chunk c of row r at LDS chunk c^(r&7)  (conflict-free b128;
//   the old unswizzled [128][32] layout had 8-way conflicts on frag reads).
// ---------------------------------------------------------------------------
template <int MODE>
__global__ __launch_bounds__(256) void gemm_kernel(
    const bf16* __restrict__ A, const bf16* __restrict__ Bt,
    const float* __restrict__ bias, int N, float* __restrict__ outf,
    bf16* __restrict__ qo, bf16* __restrict__ ko, bf16* __restrict__ vo) {
  constexpr int Kdim = 768;
  __shared__ __align__(16) bf16 As[128][64];
  __shared__ __align__(16) bf16 Bs[128][64];
  const int tid = threadIdx.x;
  const int lane = tid & 63;
  const int wave = tid >> 6;
  const int wm = (wave >> 1) * 64, wn = (wave & 1) * 64;
  const int m0 = blockIdx.y * 128, n0 = blockIdx.x * 128;
  const int l15 = lane & 15, q4 = lane >> 4;
  const int swz = l15 & 7;

  f32x4 acc[4][4] = {};

  const int gr = lane >> 3;        // row within 8-row group
  const int sj = (lane & 7) ^ gr;  // global source chunk (XOR swizzle)

  for (int k0 = 0; k0 < Kdim; k0 += 64) {
#pragma unroll
    for (int c = 0; c < 4; ++c) {
      const int r0 = wave * 32 + c * 8;  // 8-row group staged per call
      async16(A + (size_t)(m0 + r0 + gr) * Kdim + k0 + sj * 8, &As[r0][0]);
      async16(Bt + (size_t)(n0 + r0 + gr) * Kdim + k0 + sj * 8, &Bs[r0][0]);
    }
    __syncthreads();
#pragma unroll
    for (int ks = 0; ks < 2; ++ks) {
      bf16x8v af[4], bfg[4];
#pragma unroll
      for (int i = 0; i < 4; ++i)
        af[i] =
            *(const bf16x8v*)&As[wm + i * 16 + l15][((ks * 4 + q4) ^ swz) * 8];
#pragma unroll
      for (int i = 0; i < 4; ++i)
        bfg[i] =
            *(const bf16x8v*)&Bs[wn + i * 16 + l15][((ks * 4 + q4) ^ swz) * 8];
#pragma unroll
      for (int mi = 0; mi < 4; ++mi)
#pragma unroll
        for (int ni = 0; ni < 4; ++ni)
          acc[mi][ni] = MFMA_BF16(af[mi], bfg[ni], acc[mi][ni]);
    }
    __syncthreads();
  }

#pragma unroll
  for (int mi = 0; mi < 4; ++mi) {
#pragma unroll
    for (int ni = 0; ni < 4; ++ni) {
      int col = n0 + wn + ni * 16 + l15;
      float bv = bias[col];
#pragma unroll
      for (int r = 0; r < 4; ++r) {
        int row = m0 + wm + mi * 16 + q4 * 4 + r;
        float val = acc[mi][ni][r] + bv;
        if (MODE == 0) {
          outf[(size_t)row * N + col] = val;
        } else {
          int sel = col / 768;
          int cc = col - sel * 768;
          int h = cc >> 6, d = cc & 63;
          int b = row >> 12, t = row & 4095;
          bf16* dst = sel == 0 ? qo : (sel == 1 ? ko : vo);
          dst[((size_t)(b * 12 + h) * 4096 + t) * 64 + d] = (bf16)val;
        }
      }
    }
  }
}

// ---------------------------------------------------------------------------
// Flash attention — R6 kernel VERBATIM (best measured: 85.6 us).
// Mirror-pair block {63-p, p}; 8 waves, one 16-row strip per wave (waves
// 0-3 big tile, 4-7 small tile) — balanced; R8's same-tile pairing put the
// block critical path on 2 waves and regressed.
// p MAP: bh=id%24, p=id/24 (24 = 0 mod 8 -> per-bh XCD/L2 affinity; proven).
// QK^T swapped (mfma(K,Q)); P via 4 ds_write_b64; swizzled b128 PV A-frag.
// 48 KB LDS, 3 blocks/CU, launch_bounds(512,6) = 24 waves/CU.
// ---------------------------------------------------------------------------
__global__ __launch_bounds__(512, 6) void attn_kernel(
    const bf16* __restrict__ q, const bf16* __restrict__ k,
    const bf16* __restrict__ vt, bf16* __restrict__ y) {
  __shared__ __align__(16) bf16 Kb[2][64][64];  // [key][d], swizzled
  __shared__ __align__(16) bf16 Vb[2][64][64];  // [d][key], swizzled
  __shared__ __align__(16) bf16 Ps[8][16][64];  // per-wave P, swizzled
  const int tid = threadIdx.x;
  const int lane = tid & 63, wave = tid >> 6;  // wave 0..7
  const int l15 = lane & 15, q4 = lane >> 4;
  const int swz = l15 & 7;
  const int id = blockIdx.x;
  const int bh = id % 24;
  const int p = id / 24;  // 0..31
  // wave role: one 16-row strip.  waves 0-3: big tile 63-p; 4-7: small tile p
  const int rs = (wave < 4) ? ((63 - p) * 64 + wave * 16)
                            : (p * 64 + (wave - 4) * 16);
  const int hb = bh % 12, bb = bh / 12;

  // staging geometry: one async16 wave-call covers 8 rows x 8 chunks (1 KB);
  // each of 8 waves stages one 8-row group of K and of V.
  const int gr = lane >> 3;        // row within 8-row group
  const int sj = (lane & 7) ^ gr;  // global source chunk (XOR swizzle)
  const bf16* kgbase = k + (size_t)bh * 4096 * 64;
  const bf16* vgbase = vt + (size_t)bh * 64 * 4096;

  bf16x8v ones;
#pragma unroll
  for (int j = 0; j < 8; ++j) ones[j] = (bf16)1.0f;

  // Q fragments for this wave's strip, pre-scaled by log2(e)/sqrt(64)
  bf16x8v qf[2];
  {
    const bf16* qrow = q + ((size_t)bh * 4096 + rs + l15) * 64 + q4 * 8;
#pragma unroll
    for (int ks = 0; ks < 2; ++ks) {
      bf16x8v t8 = *(const bf16x8v*)(qrow + ks * 32);
#pragma unroll
      for (int j = 0; j < 8; ++j) t8[j] = (bf16)((float)t8[j] * 0.18033688f);
      qf[ks] = t8;
    }
  }

  f32x4 o[4] = {};
  f32x4 ol = {};

  auto stage = [&](int kt, int buf) {
    const int t0k = kt * 64;
    async16(kgbase + (size_t)(t0k + wave * 8 + gr) * 64 + sj * 8,
            &Kb[buf][wave * 8][0]);
    async16(vgbase + (size_t)(wave * 8 + gr) * 4096 + t0k + sj * 8,
            &Vb[buf][wave * 8][0]);
  };

  // p = exp2(s - 28.854); full (no mask) variant
  auto sm_full = [&](f32x4 (&s)[4]) {
#pragma unroll
    for (int ni = 0; ni < 4; ++ni)
#pragma unroll
      for (int r = 0; r < 4; ++r)
        s[ni][r] = __builtin_amdgcn_exp2f(s[ni][r] - 28.8539008f);
  };
  // masked variant: local key (ni*16+q4*4+r) valid iff <= lim
  auto sm_mask = [&](f32x4 (&s)[4], int lim) {
#pragma unroll
    for (int ni = 0; ni < 4; ++ni)
#pragma unroll
      for (int r = 0; r < 4; ++r)
        s[ni][r] = (ni * 16 + q4 * 4 + r <= lim)
                       ? __builtin_amdgcn_exp2f(s[ni][r] - 28.8539008f)
                       : 0.0f;
  };
  // P row write: lane (q4,l15) owns keys ni*16 + q4*4 + {0..3} of q-row l15.
  auto pwrite = [&](const f32x4 (&s)[4]) {
#pragma unroll
    for (int ni = 0; ni < 4; ++ni) {
      bf16x4v pv4;
#pragma unroll
      for (int e = 0; e < 4; ++e) pv4[e] = (bf16)s[ni][e];
      const int jb = ni * 2 + (q4 >> 1);
      *(bf16x4v*)&Ps[wave][l15][((jb ^ (l15 & 7)) * 8) + (q4 & 1) * 4] = pv4;
    }
  };

  const int ktmax = 64 - p;  // tiles needed by the big tile
  stage(0, 0);

  for (int kt = 0; kt < ktmax; ++kt) {
    const int buf = kt & 1;
    __syncthreads();  // drains vmcnt: tile kt resident; buf^1 free
    if (kt + 1 < ktmax) stage(kt + 1, buf ^ 1);
    const int t0 = kt * 64;

    if (t0 <= rs + 15) {  // wave-uniform: this strip still has work
      // S^T = K Q^T (exp2 domain)
      // Lane (q4,l15): s[ni][r] = S[qrow = rs + l15][key = t0+ni*16+q4*4+r]
      f32x4 s[4] = {};
      __builtin_amdgcn_s_setprio(1);
#pragma unroll
      for (int ni = 0; ni < 4; ++ni) {
#pragma unroll
        for (int ks = 0; ks < 2; ++ks) {
          bf16x8v kf = *(const bf16x8v*)&Kb[buf][ni * 16 + l15]
                                           [((ks * 4 + q4) ^ swz) * 8];
          s[ni] = MFMA_BF16(kf, qf[ks], s[ni]);
        }
      }
      __builtin_amdgcn_s_setprio(0);

      // softmax + P write (masked only near the diagonal)
      if (t0 + 63 <= rs) sm_full(s); else sm_mask(s, rs + l15 - t0);
      pwrite(s);

      // PV A-frag: proven swizzled b128 read path (row = q_row = l15)
      bf16x8v pf[2];
#pragma unroll
      for (int ks = 0; ks < 2; ++ks)
        pf[ks] = *(const bf16x8v*)&Ps[wave][l15][((ks * 4 + q4) ^ swz) * 8];

      // O += P V ; rowsum l += P * ones
      __builtin_amdgcn_s_setprio(1);
#pragma unroll
      for (int d4 = 0; d4 < 4; ++d4) {
#pragma unroll
        for (int ks = 0; ks < 2; ++ks) {
          bf16x8v vf = *(const bf16x8v*)&Vb[buf][d4 * 16 + l15]
                                           [((ks * 4 + q4) ^ swz) * 8];
          o[d4] = MFMA_BF16(pf[ks], vf, o[d4]);
        }
      }
#pragma unroll
      for (int ks = 0; ks < 2; ++ks) ol = MFMA_BF16(pf[ks], ones, ol);
      __builtin_amdgcn_s_setprio(0);
    }
  }

  // epilogue: y[b][t][h*64+d] = O / l  (fixed-max scale cancels)
  // PV output D-layout: q_row = rs + q4*4 + r, d = d4*16 + l15.
#pragma unroll
  for (int d4 = 0; d4 < 4; ++d4)
#pragma unroll
    for (int r = 0; r < 4; ++r) {
      int row = rs + q4 * 4 + r;
      y[((size_t)(bb * 4096 + row)) * 768 + hb * 64 + d4 * 16 + l15] =
          (bf16)(o[d4][r] / ol[r]);
    }
}

// ---------------------------------------------------------------------------
extern "C" void kernel_launch(void* const* d_in, const int* in_sizes, int n_in,
                              void* d_out, int out_size, void* d_ws,
                              size_t ws_size, hipStream_t stream) {
  const float* x = (const float*)d_in[0];       // (2,4096,768) f32
  const float* w_attn = (const float*)d_in[1];  // (768,2304) f32
  const float* b_attn = (const float*)d_in[2];  // (2304) f32
  const float* w_proj = (const float*)d_in[3];  // (768,768) f32
  const float* b_proj = (const float*)d_in[4];  // (768) f32
  float* out = (float*)d_out;                   // (8192*768) f32

  char* ws = (char*)d_ws;
  size_t off = 0;
  auto carve = [&](size_t elems) {
    char* p = ws + off;
    off += ((elems * sizeof(bf16) + 255) & ~(size_t)255);
    return (bf16*)p;
  };
  bf16* xb = carve((size_t)8192 * 768);      // x bf16; reused as vtb
  bf16* wt_attn = carve((size_t)2304 * 768);
  bf16* wt_proj = carve((size_t)768 * 768);
  bf16* qb = carve((size_t)24 * 4096 * 64);
  bf16* kb = carve((size_t)24 * 4096 * 64);
  bf16* vb = carve((size_t)24 * 4096 * 64);  // reused as yb
  bf16* vtb = xb;  // xb dead after QKV gemm
  bf16* yb = vb;   // vb dead after V transpose

  prep_kernel<<<5376, 256, 0, stream>>>(x, xb, w_attn, wt_attn, w_proj,
                                        wt_proj);
  gemm_kernel<1><<<dim3(2304 / 128, 8192 / 128), 256, 0, stream>>>(
      xb, wt_attn, b_attn, 2304, nullptr, qb, kb, vb);
  transpose_bf16_kernel<<<dim3(64 / 32, 4096 / 32, 24), 256, 0, stream>>>(
      vb, vtb, 4096, 64);
  attn_kernel<<<dim3(768), 512, 0, stream>>>(qb, kb, vtb, yb);
  gemm_kernel<0><<<dim3(768 / 128, 8192 / 128), 256, 0, stream>>>(
      yb, wt_proj, b_proj, 768, out, nullptr, nullptr, nullptr);
}